// Round 2
// baseline (213.004 us; speedup 1.0000x reference)
//
#include <hip/hip_runtime.h>
#include <hip/hip_bf16.h>

// Problem sizes (fixed)
#define BB   16
#define SS   32
#define TKK  128
#define NN   512
#define LPB  4096            // S*TK rows per batch
#define RPB  32              // rows per score-kernel block

using bf16x8 = __attribute__((ext_vector_type(8))) __bf16;
using f32x4  = __attribute__((ext_vector_type(4))) float;

__device__ inline unsigned pack_bf16(float a, float b) {
  unsigned ua = __float_as_uint(a);
  unsigned ub = __float_as_uint(b);
  ua = (ua + 0x7FFFu + ((ua >> 16) & 1u)) >> 16;   // RNE
  ub = (ub + 0x7FFFu + ((ub >> 16) & 1u)) >> 16;
  return ua | (ub << 16);
}

__device__ inline float tanh_fast(float x) {
  // tanh(x) = 1 - 2/(e^{2x}+1); stable at both extremes
  float e = __expf(2.0f * x);
  return 1.0f - 2.0f * __builtin_amdgcn_rcpf(e + 1.0f);
}

// ---------------------------------------------------------------------------
// Merged prep: blocks [0,128) repack W_h into bf16 B-fragment order;
// blocks [128,160) compute dec_fea = s_t_hat @ W_d^T + b_d.
// B-frag for 16x16x32: col m = lane&15, k = ks*32 + 16*(e>>2) + 4*(lane>>4) + (e&3)
// Wpack[(mt*16 + ks)*64 + lane] = uint4 (8 bf16)
// ---------------------------------------------------------------------------
__global__ void prep_kernel(const float* __restrict__ W_h, uint4* __restrict__ Wpack,
                            const float* __restrict__ s_t_hat,
                            const float* __restrict__ W_d,
                            const float* __restrict__ b_d,
                            float* __restrict__ decfea) {
  if (blockIdx.x < 128) {
    int idx  = blockIdx.x * 256 + threadIdx.x;        // 32768 total
    int lane = idx & 63;
    int ks   = (idx >> 6) & 15;
    int mt   = idx >> 10;
    int m    = mt * 16 + (lane & 15);
    int k0   = ks * 32 + ((lane >> 4) << 2);
    const float* wr = W_h + m * NN;
    float a0 = wr[k0 + 0],  a1 = wr[k0 + 1],  a2 = wr[k0 + 2],  a3 = wr[k0 + 3];
    float b0 = wr[k0 + 16], b1 = wr[k0 + 17], b2 = wr[k0 + 18], b3 = wr[k0 + 19];
    uint4 o;
    o.x = pack_bf16(a0, a1); o.y = pack_bf16(a2, a3);
    o.z = pack_bf16(b0, b1); o.w = pack_bf16(b2, b3);
    Wpack[idx] = o;
  } else {
    int idx = (blockIdx.x - 128) * 256 + threadIdx.x; // 8192 total
    int b = idx >> 9, m = idx & 511;
    const float4* sp = reinterpret_cast<const float4*>(s_t_hat + b * NN);
    const float4* wp = reinterpret_cast<const float4*>(W_d + m * NN);
    float acc = 0.f;
    #pragma unroll 8
    for (int i = 0; i < NN / 4; ++i) {
      float4 a = sp[i], w = wp[i];
      acc += a.x * w.x + a.y * w.y + a.z * w.z + a.w * w.w;
    }
    decfea[idx] = acc + b_d[m];
  }
}

// ---------------------------------------------------------------------------
// Main fused kernel: per 32-row tile, E = h @ W_h^T via bf16 MFMA (fp32 acc),
// then score = v . tanh(E + dec_fea + cov*W_c), weighted = beta * score.
// 256 threads = 4 waves; wave w owns m-tiles [w*8, w*8+8) (128 of 512 cols).
// RPB=32: acc = 64 VGPR, LDS = 32 KiB -> ~4 blocks/CU (16 waves, ~50% occ).
// ---------------------------------------------------------------------------
__global__ __launch_bounds__(256, 4)
void score_kernel(const float* __restrict__ h,
                  const float* __restrict__ coverage,
                  const float* __restrict__ beta,
                  const float* __restrict__ W_c,
                  const float* __restrict__ v,
                  const uint4* __restrict__ Wpack,
                  const float* __restrict__ decfea,
                  float* __restrict__ weighted) {
  // A-tile in fragment order: Afrag[(rt*16+ks)*64 + lane] = 8 bf16 (16 B)
  __shared__ __align__(16) unsigned short Afrag[RPB * NN];   // 32 KiB
  int tid  = threadIdx.x;
  int rb   = blockIdx.x;                 // 2048 blocks
  int bidx = rb >> 7;                    // 128 blocks per batch
  const float* hblk = h + (size_t)rb * RPB * NN;

  // ---- stage h tile -> bf16 frag-ordered LDS ----
  uint2* Af2 = reinterpret_cast<uint2*>(Afrag);
  #pragma unroll
  for (int i = 0; i < 16; ++i) {
    int u     = i * 256 + tid;           // uint2 index, 4096 total
    int g     = u & 1;
    int lane6 = (u >> 1) & 63;
    int ksrt  = u >> 7;                  // rt*16 + ks  (rt in 0..1)
    int row   = ((ksrt >> 4) << 4) + (lane6 & 15);
    int k0    = (ksrt & 15) * 32 + g * 16 + ((lane6 >> 4) << 2);
    float4 hv = *reinterpret_cast<const float4*>(hblk + row * NN + k0);
    uint2 p;
    p.x = pack_bf16(hv.x, hv.y);
    p.y = pack_bf16(hv.z, hv.w);
    Af2[u] = p;
  }
  __syncthreads();

  int lane = tid & 63;
  int w    = tid >> 6;

  f32x4 acc[8][2];
  const f32x4 zz = {0.f, 0.f, 0.f, 0.f};
  #pragma unroll
  for (int q = 0; q < 8; ++q)
    #pragma unroll
    for (int rt = 0; rt < 2; ++rt) acc[q][rt] = zz;

  const bf16x8* Afv = reinterpret_cast<const bf16x8*>(Afrag);
  const bf16x8* Bv  = reinterpret_cast<const bf16x8*>(Wpack);

  #pragma unroll 4
  for (int ks = 0; ks < 16; ++ks) {
    bf16x8 af[2];
    #pragma unroll
    for (int rt = 0; rt < 2; ++rt)
      af[rt] = Afv[(rt * 16 + ks) * 64 + lane];
    #pragma unroll
    for (int q = 0; q < 8; ++q) {
      int mt = w * 8 + q;
      bf16x8 bf = Bv[(mt * 16 + ks) * 64 + lane];
      #pragma unroll
      for (int rt = 0; rt < 2; ++rt)
        acc[q][rt] = __builtin_amdgcn_mfma_f32_16x16x32_bf16(af[rt], bf, acc[q][rt], 0, 0, 0);
    }
  }

  // ---- epilogue: + dec_fea + cov*W_c, tanh, v-weighted reduce over m ----
  int col = lane & 15;                   // C/D: col = lane&15
  int rhi = (lane >> 4) << 2;            // row  = (lane>>4)*4 + reg
  float cv[2][4];
  #pragma unroll
  for (int rt = 0; rt < 2; ++rt)
    #pragma unroll
    for (int r = 0; r < 4; ++r)
      cv[rt][r] = coverage[rb * RPB + rt * 16 + rhi + r];

  float sc[2][4] = {};
  #pragma unroll
  for (int q = 0; q < 8; ++q) {
    int m = (w * 8 + q) * 16 + col;
    float dv = decfea[bidx * NN + m];
    float wc = W_c[m];
    float vv = v[m];
    #pragma unroll
    for (int rt = 0; rt < 2; ++rt)
      #pragma unroll
      for (int r = 0; r < 4; ++r) {
        float x = acc[q][rt][r] + dv + cv[rt][r] * wc;
        sc[rt][r] += vv * tanh_fast(x);
      }
  }
  #pragma unroll
  for (int rt = 0; rt < 2; ++rt)
    #pragma unroll
    for (int r = 0; r < 4; ++r) {
      float s = sc[rt][r];
      s += __shfl_xor(s, 1);
      s += __shfl_xor(s, 2);
      s += __shfl_xor(s, 4);
      s += __shfl_xor(s, 8);
      sc[rt][r] = s;
    }

  __syncthreads();                       // Afrag reuse as scorebuf
  float* scorebuf = reinterpret_cast<float*>(Afrag);   // [4][32]
  if (col == 0) {
    #pragma unroll
    for (int rt = 0; rt < 2; ++rt)
      #pragma unroll
      for (int r = 0; r < 4; ++r)
        scorebuf[w * RPB + rt * 16 + rhi + r] = sc[rt][r];
  }
  __syncthreads();
  if (tid < RPB) {
    float total = scorebuf[tid] + scorebuf[RPB + tid] + scorebuf[2 * RPB + tid] + scorebuf[3 * RPB + tid];
    int gl = rb * RPB + tid;
    int lb = gl & (LPB - 1);
    int s  = lb >> 7;                    // TK = 128
    weighted[bidx * LPB + lb] = beta[bidx * SS + s] * total;
  }
}

// ---------------------------------------------------------------------------
// Softmax over 4096 per batch, mask, renormalize; write attn_dist + coverage_new.
// Also zeroes c_t for the following atomic-accumulate kernel.
// ---------------------------------------------------------------------------
__global__ void softmax_kernel(const float* __restrict__ coverage,
                               const float* __restrict__ mask,
                               float* __restrict__ out) {
  int b = blockIdx.x;
  int t = threadIdx.x;
  float* ct   = out;                     // [0, 8192)
  float* attn = out + 8192;              // weighted in, attn_dist out
  float* covn = out + 8192 + 65536;      // coverage_new

  ct[b * NN + t] = 0.f;
  ct[b * NN + 256 + t] = 0.f;

  float wv[16];
  float mx = -1e30f;
  #pragma unroll
  for (int i = 0; i < 16; ++i) {
    wv[i] = attn[b * LPB + i * 256 + t];
    mx = fmaxf(mx, wv[i]);
  }
  __shared__ float redm[4], reds[4];
  mx = fmaxf(mx, __shfl_xor(mx, 1));
  mx = fmaxf(mx, __shfl_xor(mx, 2));
  mx = fmaxf(mx, __shfl_xor(mx, 4));
  mx = fmaxf(mx, __shfl_xor(mx, 8));
  mx = fmaxf(mx, __shfl_xor(mx, 16));
  mx = fmaxf(mx, __shfl_xor(mx, 32));
  if ((t & 63) == 0) redm[t >> 6] = mx;
  __syncthreads();
  mx = fmaxf(fmaxf(redm[0], redm[1]), fmaxf(redm[2], redm[3]));

  float e[16];
  float sum = 0.f;
  #pragma unroll
  for (int i = 0; i < 16; ++i) {
    e[i] = __expf(wv[i] - mx) * mask[b * LPB + i * 256 + t];
    sum += e[i];
  }
  sum += __shfl_xor(sum, 1);
  sum += __shfl_xor(sum, 2);
  sum += __shfl_xor(sum, 4);
  sum += __shfl_xor(sum, 8);
  sum += __shfl_xor(sum, 16);
  sum += __shfl_xor(sum, 32);
  if ((t & 63) == 0) reds[t >> 6] = sum;
  __syncthreads();
  sum = reds[0] + reds[1] + reds[2] + reds[3];
  float inv = 1.0f / sum;
  #pragma unroll
  for (int i = 0; i < 16; ++i) {
    int l = i * 256 + t;
    float a = e[i] * inv;
    attn[b * LPB + l] = a;
    covn[b * LPB + l] = coverage[b * LPB + l] + a;
  }
}

// ---------------------------------------------------------------------------
// c_t[b][n] = sum_l attn[b][l] * h[b][l][n]  (memory-bound, atomic partials)
// ---------------------------------------------------------------------------
__global__ void ct_kernel(const float* __restrict__ h, float* __restrict__ out) {
  int blk   = blockIdx.x;                // 1024
  int b     = blk >> 6;
  int chunk = blk & 63;
  int t     = threadIdx.x;
  const float* attn = out + 8192 + b * LPB + chunk * 64;
  __shared__ float as_[64];
  if (t < 64) as_[t] = attn[t];
  __syncthreads();
  const float* hp = h + (size_t)(b * LPB + chunk * 64) * NN;
  float a0 = 0.f, a1 = 0.f;
  #pragma unroll 4
  for (int r = 0; r < 64; ++r) {
    float2 hv = *reinterpret_cast<const float2*>(hp + r * NN + t * 2);
    float av = as_[r];
    a0 += av * hv.x;
    a1 += av * hv.y;
  }
  atomicAdd(&out[b * NN + t * 2],     a0);
  atomicAdd(&out[b * NN + t * 2 + 1], a1);
}

extern "C" void kernel_launch(void* const* d_in, const int* in_sizes, int n_in,
                              void* d_out, int out_size, void* d_ws, size_t ws_size,
                              hipStream_t stream) {
  const float* s_t_hat  = (const float*)d_in[0];
  const float* h        = (const float*)d_in[1];
  const float* coverage = (const float*)d_in[2];
  const float* mask     = (const float*)d_in[3];
  const float* beta     = (const float*)d_in[4];
  const float* W_h      = (const float*)d_in[5];
  const float* W_c      = (const float*)d_in[6];
  const float* W_d      = (const float*)d_in[7];
  const float* b_d      = (const float*)d_in[8];
  const float* v        = (const float*)d_in[9];
  float* out = (float*)d_out;

  uint4* Wpack    = (uint4*)d_ws;           // 512 KiB
  float* decfea   = out + 8192 + 65536;     // staged in coverage_new region
  float* weighted = out + 8192;             // staged in attn_dist region

  prep_kernel <<<160, 256, 0, stream>>>(W_h, Wpack, s_t_hat, W_d, b_d, decfea);
  score_kernel<<<2048, 256, 0, stream>>>(h, coverage, beta, W_c, v, Wpack, decfea, weighted);
  softmax_kernel<<<16, 256, 0, stream>>>(coverage, mask, out);
  ct_kernel<<<1024, 256, 0, stream>>>(h, out);
}

// Round 3
// 105.146 us; speedup vs baseline: 2.0258x; 2.0258x over previous
//
#include <hip/hip_runtime.h>
#include <hip/hip_bf16.h>

// Problem sizes (fixed)
#define BB   16
#define SS   32
#define TKK  128
#define NN   512
#define LPB  4096            // S*TK rows per batch
#define RPB  64              // rows per score-kernel block

using bf16x8 = __attribute__((ext_vector_type(8))) __bf16;
using f32x4  = __attribute__((ext_vector_type(4))) float;

__device__ inline unsigned pack_bf16(float a, float b) {
  unsigned ua = __float_as_uint(a);
  unsigned ub = __float_as_uint(b);
  ua = (ua + 0x7FFFu + ((ua >> 16) & 1u)) >> 16;   // RNE
  ub = (ub + 0x7FFFu + ((ub >> 16) & 1u)) >> 16;
  return ua | (ub << 16);
}

__device__ inline float tanh_fast(float x) {
  // tanh(x) = 1 - 2/(e^{2x}+1); stable at both extremes
  float e = __expf(2.0f * x);
  return 1.0f - 2.0f * __builtin_amdgcn_rcpf(e + 1.0f);
}

// ---------------------------------------------------------------------------
// Merged prep: blocks [0,128) repack W_h into bf16 MFMA B-fragment order;
// blocks [128,160) compute dec_fea = s_t_hat @ W_d^T + b_d.
// B-frag for 16x16x32: col m = lane&15, k = ks*32 + 16*(e>>2) + 4*(lane>>4) + (e&3)
// Wpack[(mt*16 + ks)*64 + lane] = uint4 (8 bf16)
// ---------------------------------------------------------------------------
__global__ void prep_kernel(const float* __restrict__ W_h, uint4* __restrict__ Wpack,
                            const float* __restrict__ s_t_hat,
                            const float* __restrict__ W_d,
                            const float* __restrict__ b_d,
                            float* __restrict__ decfea) {
  if (blockIdx.x < 128) {
    int idx  = blockIdx.x * 256 + threadIdx.x;        // 32768 total
    int lane = idx & 63;
    int ks   = (idx >> 6) & 15;
    int mt   = idx >> 10;
    int m    = mt * 16 + (lane & 15);
    int k0   = ks * 32 + ((lane >> 4) << 2);
    const float* wr = W_h + m * NN;
    float a0 = wr[k0 + 0],  a1 = wr[k0 + 1],  a2 = wr[k0 + 2],  a3 = wr[k0 + 3];
    float b0 = wr[k0 + 16], b1 = wr[k0 + 17], b2 = wr[k0 + 18], b3 = wr[k0 + 19];
    uint4 o;
    o.x = pack_bf16(a0, a1); o.y = pack_bf16(a2, a3);
    o.z = pack_bf16(b0, b1); o.w = pack_bf16(b2, b3);
    Wpack[idx] = o;
  } else {
    int idx = (blockIdx.x - 128) * 256 + threadIdx.x; // 8192 total
    int b = idx >> 9, m = idx & 511;
    const float4* sp = reinterpret_cast<const float4*>(s_t_hat + b * NN);
    const float4* wp = reinterpret_cast<const float4*>(W_d + m * NN);
    float acc = 0.f;
    #pragma unroll 8
    for (int i = 0; i < NN / 4; ++i) {
      float4 a = sp[i], w = wp[i];
      acc += a.x * w.x + a.y * w.y + a.z * w.z + a.w * w.w;
    }
    decfea[idx] = acc + b_d[m];
  }
}

// ---------------------------------------------------------------------------
// Main fused kernel: per 64-row tile, E = h @ W_h^T via bf16 MFMA (fp32 acc),
// then score = v . tanh(E + dec_fea + cov*W_c), weighted = beta * score.
// 512 threads = 8 waves; wave w owns m-tiles [w*4, w*4+4) (64 of 512 cols),
// and ALL 4 row-tiles. acc = 64 regs/wave, LDS = 64 KiB -> 2 blocks/CU
// (16 waves/CU, ~50% occupancy). Sum over m is separable through v.tanh,
// so waves reduce their own columns; 8-way LDS reduce at the end.
// ---------------------------------------------------------------------------
__global__ __launch_bounds__(512, 4)
void score_kernel(const float* __restrict__ h,
                  const float* __restrict__ coverage,
                  const float* __restrict__ beta,
                  const float* __restrict__ W_c,
                  const float* __restrict__ v,
                  const uint4* __restrict__ Wpack,
                  const float* __restrict__ decfea,
                  float* __restrict__ weighted) {
  // A-tile in fragment order: Afrag[(rt*16+ks)*64 + lane] = 8 bf16 (16 B)
  __shared__ __align__(16) unsigned short Afrag[RPB * NN];   // 64 KiB
  int tid  = threadIdx.x;
  int rb   = blockIdx.x;                 // 1024 blocks
  int bidx = rb >> 6;                    // 64 blocks per batch
  const float* hblk = h + (size_t)rb * RPB * NN;

  // ---- stage h tile -> bf16 frag-ordered LDS ----
  uint2* Af2 = reinterpret_cast<uint2*>(Afrag);
  #pragma unroll
  for (int i = 0; i < 16; ++i) {
    int u     = i * 512 + tid;           // uint2 index, 8192 total
    int g     = u & 1;
    int lane6 = (u >> 1) & 63;
    int ksrt  = u >> 7;                  // rt*16 + ks  (rt in 0..3)
    int row   = ((ksrt >> 4) << 4) + (lane6 & 15);
    int k0    = (ksrt & 15) * 32 + g * 16 + ((lane6 >> 4) << 2);
    float4 hv = *reinterpret_cast<const float4*>(hblk + row * NN + k0);
    uint2 p;
    p.x = pack_bf16(hv.x, hv.y);
    p.y = pack_bf16(hv.z, hv.w);
    Af2[u] = p;
  }
  __syncthreads();

  int lane = tid & 63;
  int w    = tid >> 6;                   // wave id, 0..7

  f32x4 acc[4][4];
  const f32x4 zz = {0.f, 0.f, 0.f, 0.f};
  #pragma unroll
  for (int q = 0; q < 4; ++q)
    #pragma unroll
    for (int rt = 0; rt < 4; ++rt) acc[q][rt] = zz;

  const bf16x8* Afv = reinterpret_cast<const bf16x8*>(Afrag);
  const bf16x8* Bv  = reinterpret_cast<const bf16x8*>(Wpack) + (size_t)(w * 4) * 16 * 64 + lane;

  // software-prefetched B: load ks+1 frags while MFMAing ks
  bf16x8 bf[4];
  #pragma unroll
  for (int q = 0; q < 4; ++q)
    bf[q] = Bv[(q * 16 + 0) * 64];
  for (int ks = 0; ks < 16; ++ks) {
    bf16x8 af[4];
    #pragma unroll
    for (int rt = 0; rt < 4; ++rt)
      af[rt] = Afv[(rt * 16 + ks) * 64 + lane];
    bf16x8 bn[4];
    if (ks < 15) {
      #pragma unroll
      for (int q = 0; q < 4; ++q)
        bn[q] = Bv[(q * 16 + ks + 1) * 64];
    }
    #pragma unroll
    for (int q = 0; q < 4; ++q)
      #pragma unroll
      for (int rt = 0; rt < 4; ++rt)
        acc[q][rt] = __builtin_amdgcn_mfma_f32_16x16x32_bf16(af[rt], bf[q], acc[q][rt], 0, 0, 0);
    #pragma unroll
    for (int q = 0; q < 4; ++q) bf[q] = bn[q];
  }

  // ---- epilogue: + dec_fea + cov*W_c, tanh, v-weighted reduce over m ----
  int col = lane & 15;                   // C/D: col = lane&15
  int rhi = (lane >> 4) << 2;            // row  = (lane>>4)*4 + reg
  float cv[4][4];
  #pragma unroll
  for (int rt = 0; rt < 4; ++rt)
    #pragma unroll
    for (int r = 0; r < 4; ++r)
      cv[rt][r] = coverage[rb * RPB + rt * 16 + rhi + r];

  float sc[4][4] = {};
  #pragma unroll
  for (int q = 0; q < 4; ++q) {
    int m = (w * 4 + q) * 16 + col;
    float dv = decfea[bidx * NN + m];
    float wc = W_c[m];
    float vv = v[m];
    #pragma unroll
    for (int rt = 0; rt < 4; ++rt)
      #pragma unroll
      for (int r = 0; r < 4; ++r) {
        float x = acc[q][rt][r] + dv + cv[rt][r] * wc;
        sc[rt][r] += vv * tanh_fast(x);
      }
  }
  #pragma unroll
  for (int rt = 0; rt < 4; ++rt)
    #pragma unroll
    for (int r = 0; r < 4; ++r) {
      float s = sc[rt][r];
      s += __shfl_xor(s, 1);
      s += __shfl_xor(s, 2);
      s += __shfl_xor(s, 4);
      s += __shfl_xor(s, 8);
      sc[rt][r] = s;
    }

  __syncthreads();                       // Afrag reads done; reuse as scorebuf
  float* scorebuf = reinterpret_cast<float*>(Afrag);   // [8][64]
  if (col == 0) {
    #pragma unroll
    for (int rt = 0; rt < 4; ++rt)
      #pragma unroll
      for (int r = 0; r < 4; ++r)
        scorebuf[w * RPB + rt * 16 + rhi + r] = sc[rt][r];
  }
  __syncthreads();
  if (tid < RPB) {
    float total = 0.f;
    #pragma unroll
    for (int ww = 0; ww < 8; ++ww) total += scorebuf[ww * RPB + tid];
    int gl = rb * RPB + tid;
    int lb = gl & (LPB - 1);
    int s  = lb >> 7;                    // TK = 128
    weighted[bidx * LPB + lb] = beta[bidx * SS + s] * total;
  }
}

// ---------------------------------------------------------------------------
// Softmax over 4096 per batch, mask, renormalize; write attn_dist + coverage_new.
// Also zeroes c_t for the following atomic-accumulate kernel.
// ---------------------------------------------------------------------------
__global__ void softmax_kernel(const float* __restrict__ coverage,
                               const float* __restrict__ mask,
                               float* __restrict__ out) {
  int b = blockIdx.x;
  int t = threadIdx.x;
  float* ct   = out;                     // [0, 8192)
  float* attn = out + 8192;              // weighted in, attn_dist out
  float* covn = out + 8192 + 65536;      // coverage_new

  ct[b * NN + t] = 0.f;
  ct[b * NN + 256 + t] = 0.f;

  float wv[16];
  float mx = -1e30f;
  #pragma unroll
  for (int i = 0; i < 16; ++i) {
    wv[i] = attn[b * LPB + i * 256 + t];
    mx = fmaxf(mx, wv[i]);
  }
  __shared__ float redm[4], reds[4];
  mx = fmaxf(mx, __shfl_xor(mx, 1));
  mx = fmaxf(mx, __shfl_xor(mx, 2));
  mx = fmaxf(mx, __shfl_xor(mx, 4));
  mx = fmaxf(mx, __shfl_xor(mx, 8));
  mx = fmaxf(mx, __shfl_xor(mx, 16));
  mx = fmaxf(mx, __shfl_xor(mx, 32));
  if ((t & 63) == 0) redm[t >> 6] = mx;
  __syncthreads();
  mx = fmaxf(fmaxf(redm[0], redm[1]), fmaxf(redm[2], redm[3]));

  float e[16];
  float sum = 0.f;
  #pragma unroll
  for (int i = 0; i < 16; ++i) {
    e[i] = __expf(wv[i] - mx) * mask[b * LPB + i * 256 + t];
    sum += e[i];
  }
  sum += __shfl_xor(sum, 1);
  sum += __shfl_xor(sum, 2);
  sum += __shfl_xor(sum, 4);
  sum += __shfl_xor(sum, 8);
  sum += __shfl_xor(sum, 16);
  sum += __shfl_xor(sum, 32);
  if ((t & 63) == 0) reds[t >> 6] = sum;
  __syncthreads();
  sum = reds[0] + reds[1] + reds[2] + reds[3];
  float inv = 1.0f / sum;
  #pragma unroll
  for (int i = 0; i < 16; ++i) {
    int l = i * 256 + t;
    float a = e[i] * inv;
    attn[b * LPB + l] = a;
    covn[b * LPB + l] = coverage[b * LPB + l] + a;
  }
}

// ---------------------------------------------------------------------------
// c_t[b][n] = sum_l attn[b][l] * h[b][l][n]  (memory-bound, atomic partials)
// ---------------------------------------------------------------------------
__global__ void ct_kernel(const float* __restrict__ h, float* __restrict__ out) {
  int blk   = blockIdx.x;                // 1024
  int b     = blk >> 6;
  int chunk = blk & 63;
  int t     = threadIdx.x;
  const float* attn = out + 8192 + b * LPB + chunk * 64;
  __shared__ float as_[64];
  if (t < 64) as_[t] = attn[t];
  __syncthreads();
  const float* hp = h + (size_t)(b * LPB + chunk * 64) * NN;
  float a0 = 0.f, a1 = 0.f;
  #pragma unroll 4
  for (int r = 0; r < 64; ++r) {
    float2 hv = *reinterpret_cast<const float2*>(hp + r * NN + t * 2);
    float av = as_[r];
    a0 += av * hv.x;
    a1 += av * hv.y;
  }
  atomicAdd(&out[b * NN + t * 2],     a0);
  atomicAdd(&out[b * NN + t * 2 + 1], a1);
}

extern "C" void kernel_launch(void* const* d_in, const int* in_sizes, int n_in,
                              void* d_out, int out_size, void* d_ws, size_t ws_size,
                              hipStream_t stream) {
  const float* s_t_hat  = (const float*)d_in[0];
  const float* h        = (const float*)d_in[1];
  const float* coverage = (const float*)d_in[2];
  const float* mask     = (const float*)d_in[3];
  const float* beta     = (const float*)d_in[4];
  const float* W_h      = (const float*)d_in[5];
  const float* W_c      = (const float*)d_in[6];
  const float* W_d      = (const float*)d_in[7];
  const float* b_d      = (const float*)d_in[8];
  const float* v        = (const float*)d_in[9];
  float* out = (float*)d_out;

  uint4* Wpack    = (uint4*)d_ws;           // 512 KiB
  float* decfea   = out + 8192 + 65536;     // staged in coverage_new region
  float* weighted = out + 8192;             // staged in attn_dist region

  prep_kernel <<<160, 256, 0, stream>>>(W_h, Wpack, s_t_hat, W_d, b_d, decfea);
  score_kernel<<<1024, 512, 0, stream>>>(h, coverage, beta, W_c, v, Wpack, decfea, weighted);
  softmax_kernel<<<16, 256, 0, stream>>>(coverage, mask, out);
  ct_kernel<<<1024, 256, 0, stream>>>(h, out);
}